// Round 1
// baseline (985.190 us; speedup 1.0000x reference)
//
#include <hip/hip_runtime.h>

typedef float  f32x4 __attribute__((ext_vector_type(4)));
typedef _Float16 f16x4 __attribute__((ext_vector_type(4)));
typedef _Float16 f16x8 __attribute__((ext_vector_type(8)));

#define BM 64
#define BN 64
#define BK 32
#define BKP 40   // padded LDS leading dim (halfs): 80B rows, 16B-aligned, spreads banks

// ---------------------------------------------------------------------------
// K1: qout[M,N] (fp16) = query[M,K] (fp32) * W[N,K]^T (fp32) + bias[N]
// M=16384 (B*Lq), N=1024 (Dout), K=1024 (Din)
// ---------------------------------------------------------------------------
__global__ __launch_bounds__(256) void proj_kernel(
    const float* __restrict__ query, const float* __restrict__ W,
    const float* __restrict__ bias, _Float16* __restrict__ qout) {
  const int K = 1024, N = 1024;
  __shared__ _Float16 As[BM][BKP];
  __shared__ _Float16 Bs[BN][BKP];
  int tid = threadIdx.x;
  int m0 = blockIdx.x * BM, n0 = blockIdx.y * BN;
  int lane = tid & 63, wv = tid >> 6;
  int k8 = (lane >> 4) * 8;
  f32x4 acc[4] = {};
  for (int k0 = 0; k0 < K; k0 += BK) {
    #pragma unroll
    for (int it = 0; it < 2; it++) {          // 512 float4 per tile / 256 thr
      int idx = tid + it * 256;
      int r = idx >> 3, c = (idx & 7) * 4;
      f32x4 v = *(const f32x4*)&query[(size_t)(m0 + r) * K + k0 + c];
      f16x4 h = {(_Float16)v[0], (_Float16)v[1], (_Float16)v[2], (_Float16)v[3]};
      *(f16x4*)&As[r][c] = h;
      f32x4 w = *(const f32x4*)&W[(size_t)(n0 + r) * K + k0 + c];
      f16x4 hw = {(_Float16)w[0], (_Float16)w[1], (_Float16)w[2], (_Float16)w[3]};
      *(f16x4*)&Bs[r][c] = hw;
    }
    __syncthreads();
    f16x8 af = *(const f16x8*)&As[wv * 16 + (lane & 15)][k8];
    #pragma unroll
    for (int t = 0; t < 4; t++) {
      f16x8 bf = *(const f16x8*)&Bs[t * 16 + (lane & 15)][k8];
      acc[t] = __builtin_amdgcn_mfma_f32_16x16x32_f16(af, bf, acc[t], 0, 0, 0);
    }
    __syncthreads();
  }
  #pragma unroll
  for (int t = 0; t < 4; t++) {
    int gcol = n0 + t * 16 + (lane & 15);
    float bb = bias[gcol];
    #pragma unroll
    for (int r = 0; r < 4; r++) {
      int grow = m0 + wv * 16 + (lane >> 4) * 4 + r;
      qout[(size_t)grow * N + gcol] = (_Float16)(acc[t][r] + bb);
    }
  }
}

// ---------------------------------------------------------------------------
// K2: logits[b][Lq,Lm] (fp16) = qf16[b][Lq,K] * mem[b][Lm,K]^T   (no mask yet)
// ---------------------------------------------------------------------------
__global__ __launch_bounds__(256) void scores_kernel(
    const _Float16* __restrict__ qf16, const float* __restrict__ mem,
    _Float16* __restrict__ wbuf) {
  const int K = 1024, Lm = 2048, Lq = 2048;
  __shared__ _Float16 As[BM][BKP];
  __shared__ _Float16 Bs[BN][BKP];
  int tid = threadIdx.x;
  int b = blockIdx.z;
  int n0 = blockIdx.x * BN, m0 = blockIdx.y * BM;
  const _Float16* A = qf16 + (size_t)b * Lq * K;
  const float* Bp = mem + (size_t)b * Lm * K;
  int lane = tid & 63, wv = tid >> 6;
  int k8 = (lane >> 4) * 8;
  f32x4 acc[4] = {};
  for (int k0 = 0; k0 < K; k0 += BK) {
    {  // A tile: fp16 straight copy, 16B per thread
      int r = tid >> 2, c8 = (tid & 3) * 8;
      *(f16x8*)&As[r][c8] = *(const f16x8*)&A[(size_t)(m0 + r) * K + k0 + c8];
    }
    #pragma unroll
    for (int it = 0; it < 2; it++) {  // B tile: fp32 load + cvt
      int idx = tid + it * 256;
      int r = idx >> 3, c = (idx & 7) * 4;
      f32x4 v = *(const f32x4*)&Bp[(size_t)(n0 + r) * K + k0 + c];
      f16x4 h = {(_Float16)v[0], (_Float16)v[1], (_Float16)v[2], (_Float16)v[3]};
      *(f16x4*)&Bs[r][c] = h;
    }
    __syncthreads();
    f16x8 af = *(const f16x8*)&As[wv * 16 + (lane & 15)][k8];
    #pragma unroll
    for (int t = 0; t < 4; t++) {
      f16x8 bf = *(const f16x8*)&Bs[t * 16 + (lane & 15)][k8];
      acc[t] = __builtin_amdgcn_mfma_f32_16x16x32_f16(af, bf, acc[t], 0, 0, 0);
    }
    __syncthreads();
  }
  _Float16* out = wbuf + (size_t)b * Lq * Lm;
  #pragma unroll
  for (int t = 0; t < 4; t++) {
    int gcol = n0 + t * 16 + (lane & 15);
    #pragma unroll
    for (int r = 0; r < 4; r++) {
      int grow = m0 + wv * 16 + (lane >> 4) * 4 + r;
      out[(size_t)grow * Lm + gcol] = (_Float16)acc[t][r];
    }
  }
}

// ---------------------------------------------------------------------------
// K3: per-row mask + softmax, in place over the fp16 logits buffer.
// One block per (b,q) row; each thread holds 8 elements in regs.
// ---------------------------------------------------------------------------
__global__ __launch_bounds__(256) void softmax_kernel(
    const int* __restrict__ mask, _Float16* __restrict__ wbuf) {
  const int Lm = 2048;
  size_t row = blockIdx.x;
  _Float16* wr = wbuf + row * Lm;
  const int* mr = mask + row * Lm;
  int tid = threadIdx.x;
  float v[8];
  float mx = -3.0e38f;
  #pragma unroll
  for (int i = 0; i < 8; i++) {
    int c = tid + i * 256;
    float l = (float)wr[c];
    if (mr[c] == 0) l += -1000000.0f;
    v[i] = l;
    mx = fmaxf(mx, l);
  }
  #pragma unroll
  for (int off = 32; off > 0; off >>= 1) mx = fmaxf(mx, __shfl_down(mx, off, 64));
  __shared__ float red[4];
  int wv = tid >> 6;
  if ((tid & 63) == 0) red[wv] = mx;
  __syncthreads();
  mx = fmaxf(fmaxf(red[0], red[1]), fmaxf(red[2], red[3]));
  __syncthreads();
  float s = 0.f;
  #pragma unroll
  for (int i = 0; i < 8; i++) { v[i] = __expf(v[i] - mx); s += v[i]; }
  #pragma unroll
  for (int off = 32; off > 0; off >>= 1) s += __shfl_down(s, off, 64);
  if ((tid & 63) == 0) red[wv] = s;
  __syncthreads();
  float inv = 1.0f / (red[0] + red[1] + red[2] + red[3]);
  #pragma unroll
  for (int i = 0; i < 8; i++) wr[tid + i * 256] = (_Float16)(v[i] * inv);
}

// ---------------------------------------------------------------------------
// K4: out[b][Lq,N] (fp32) = weights[b][Lq,K=Lm] (fp16) * mem[b][K,N] (fp32)
// B operand is NOT transposed -> transpose during LDS staging.
// ---------------------------------------------------------------------------
__global__ __launch_bounds__(256) void pv_kernel(
    const _Float16* __restrict__ wbuf, const float* __restrict__ mem,
    float* __restrict__ out) {
  const int K = 2048, N = 1024, Lq = 2048;
  __shared__ _Float16 As[BM][BKP];
  __shared__ _Float16 Bs[BN][BKP];
  int tid = threadIdx.x;
  int b = blockIdx.z;
  int n0 = blockIdx.x * BN, m0 = blockIdx.y * BM;
  const _Float16* A = wbuf + (size_t)b * Lq * K;
  const float* Bp = mem + (size_t)b * K * N;
  int lane = tid & 63, wv = tid >> 6;
  int k8 = (lane >> 4) * 8;
  f32x4 acc[4] = {};
  for (int k0 = 0; k0 < K; k0 += BK) {
    {  // A tile: fp16 weights, straight copy
      int r = tid >> 2, c8 = (tid & 3) * 8;
      *(f16x8*)&As[r][c8] = *(const f16x8*)&A[(size_t)(m0 + r) * K + k0 + c8];
    }
    #pragma unroll
    for (int it = 0; it < 2; it++) {  // B tile: fp32 load, cvt, transpose into Bs[n][k]
      int idx = tid + it * 256;
      int kk = idx >> 4, n4 = (idx & 15) * 4;
      f32x4 v = *(const f32x4*)&Bp[(size_t)(k0 + kk) * N + n0 + n4];
      #pragma unroll
      for (int j = 0; j < 4; j++) Bs[n4 + j][kk] = (_Float16)v[j];
    }
    __syncthreads();
    f16x8 af = *(const f16x8*)&As[wv * 16 + (lane & 15)][k8];
    #pragma unroll
    for (int t = 0; t < 4; t++) {
      f16x8 bf = *(const f16x8*)&Bs[t * 16 + (lane & 15)][k8];
      acc[t] = __builtin_amdgcn_mfma_f32_16x16x32_f16(af, bf, acc[t], 0, 0, 0);
    }
    __syncthreads();
  }
  #pragma unroll
  for (int t = 0; t < 4; t++) {
    int gcol = n0 + t * 16 + (lane & 15);
    #pragma unroll
    for (int r = 0; r < 4; r++) {
      int grow = m0 + wv * 16 + (lane >> 4) * 4 + r;
      out[((size_t)b * Lq + grow) * N + gcol] = acc[t][r];
    }
  }
}

// ---------------------------------------------------------------------------
// B=8, Lq=Lm=2048, Din=Dout=1024
// ws layout: [0, 32MB)  q fp16 [B*Lq, 1024]
//            [32MB, 96MB) logits->weights fp16 [B, Lq, Lm] (softmax in place)
// total ws needed: 100,663,296 bytes
// ---------------------------------------------------------------------------
extern "C" void kernel_launch(void* const* d_in, const int* in_sizes, int n_in,
                              void* d_out, int out_size, void* d_ws, size_t ws_size,
                              hipStream_t stream) {
  const float* query = (const float*)d_in[0];
  const float* mem   = (const float*)d_in[1];
  const int*   mask  = (const int*)d_in[2];
  const float* W     = (const float*)d_in[3];
  const float* bias  = (const float*)d_in[4];
  float* out = (float*)d_out;

  _Float16* qf16 = (_Float16*)d_ws;
  _Float16* wbuf = (_Float16*)((char*)d_ws + (size_t)16384 * 1024 * 2);

  proj_kernel<<<dim3(256, 16), 256, 0, stream>>>(query, W, bias, qf16);
  scores_kernel<<<dim3(32, 32, 8), 256, 0, stream>>>(qf16, mem, wbuf);
  softmax_kernel<<<dim3(16384), 256, 0, stream>>>(mask, wbuf);
  pv_kernel<<<dim3(16, 32, 8), 256, 0, stream>>>(wbuf, mem, out);
}

// Round 6
// 641.906 us; speedup vs baseline: 1.5348x; 1.5348x over previous
//
#include <hip/hip_runtime.h>

typedef float    f32x4 __attribute__((ext_vector_type(4)));
typedef _Float16 f16x4 __attribute__((ext_vector_type(4)));
typedef _Float16 f16x8 __attribute__((ext_vector_type(8)));

// ---------------------------------------------------------------------------
// Unified 128x128 GEMM, C = A * B^T (+bias), fp32 accum, 16x16x32 f16 MFMA.
// A: [M,K], B: [N,K] row-major. All staging is MANUAL (VGPR round-trip):
//  - fp16 operand: f16x8 straight copy into unpadded 32-half rows (64B
//    stride; b128 frag reads and 16B/lane writes are bank-uniform).
//  - fp32 operand: f32x4 load + cvt into 40-half-stride tile (80B rows,
//    16B-aligned; <=2-way bank alias on write and read = free per m136).
// ---------------------------------------------------------------------------
template <typename TOUT, bool AF16, bool BF16, bool BIAS>
__global__ __launch_bounds__(256) void gemm128(
    const void* __restrict__ Ap, const void* __restrict__ Bp,
    const float* __restrict__ bias, TOUT* __restrict__ Cp,
    int M, int N, int K, long sA, long sB, long sC) {
  constexpr int LA = AF16 ? 32 : 40;
  constexpr int LB = BF16 ? 32 : 40;
  __shared__ _Float16 As[128 * LA];
  __shared__ _Float16 Bs[128 * LB];
  const int tid = threadIdx.x;
  const int lane = tid & 63, wv = tid >> 6;
  const int wr = (wv >> 1) * 64, wc = (wv & 1) * 64;
  const int l15 = lane & 15, k8 = (lane >> 4) * 8;
  const int m0 = blockIdx.y * 128, n0 = blockIdx.x * 128;
  const _Float16* A16 = (const _Float16*)Ap + (size_t)blockIdx.z * sA;
  const float*    A32 = (const float*)Ap    + (size_t)blockIdx.z * sA;
  const _Float16* B16 = (const _Float16*)Bp + (size_t)blockIdx.z * sB;
  const float*    B32 = (const float*)Bp    + (size_t)blockIdx.z * sB;

  f32x4 acc[4][4] = {};

  for (int k0 = 0; k0 < K; k0 += 32) {
    if constexpr (AF16) {
      #pragma unroll
      for (int r = 0; r < 2; r++) {           // 128x32 halfs, 16B/thread x2
        int c = r * 256 + tid;
        int row = c >> 2, c8 = (c & 3) * 8;
        *(f16x8*)&As[row * LA + c8] =
            *(const f16x8*)&A16[(size_t)(m0 + row) * K + k0 + c8];
      }
    } else {
      #pragma unroll
      for (int r = 0; r < 4; r++) {           // fp32 load + cvt
        int c = r * 256 + tid;
        int row = c >> 3, c4 = (c & 7) * 4;
        f32x4 v = *(const f32x4*)(A32 + (size_t)(m0 + row) * K + k0 + c4);
        f16x4 h = {(_Float16)v[0], (_Float16)v[1], (_Float16)v[2], (_Float16)v[3]};
        *(f16x4*)&As[row * LA + c4] = h;
      }
    }
    if constexpr (BF16) {
      #pragma unroll
      for (int r = 0; r < 2; r++) {
        int c = r * 256 + tid;
        int row = c >> 2, c8 = (c & 3) * 8;
        *(f16x8*)&Bs[row * LB + c8] =
            *(const f16x8*)&B16[(size_t)(n0 + row) * K + k0 + c8];
      }
    } else {
      #pragma unroll
      for (int r = 0; r < 4; r++) {
        int c = r * 256 + tid;
        int row = c >> 3, c4 = (c & 7) * 4;
        f32x4 v = *(const f32x4*)(B32 + (size_t)(n0 + row) * K + k0 + c4);
        f16x4 h = {(_Float16)v[0], (_Float16)v[1], (_Float16)v[2], (_Float16)v[3]};
        *(f16x4*)&Bs[row * LB + c4] = h;
      }
    }
    __syncthreads();
    f16x8 af[4], bf[4];
    #pragma unroll
    for (int i = 0; i < 4; i++)
      af[i] = *(const f16x8*)&As[(wr + i * 16 + l15) * LA + k8];
    #pragma unroll
    for (int j = 0; j < 4; j++)
      bf[j] = *(const f16x8*)&Bs[(wc + j * 16 + l15) * LB + k8];
    #pragma unroll
    for (int i = 0; i < 4; i++)
      #pragma unroll
      for (int j = 0; j < 4; j++)
        acc[i][j] = __builtin_amdgcn_mfma_f32_16x16x32_f16(af[i], bf[j],
                                                           acc[i][j], 0, 0, 0);
    __syncthreads();
  }

  TOUT* C = Cp + (size_t)blockIdx.z * sC;
  const int q4 = (lane >> 4) * 4;
  #pragma unroll
  for (int j = 0; j < 4; j++) {
    int col = n0 + wc + j * 16 + l15;
    float bb = BIAS ? bias[col] : 0.0f;
    #pragma unroll
    for (int i = 0; i < 4; i++) {
      int rowb = m0 + wr + i * 16 + q4;
      #pragma unroll
      for (int rr = 0; rr < 4; rr++)
        C[(size_t)(rowb + rr) * N + col] = (TOUT)(acc[i][j][rr] + bb);
    }
  }
}

// ---------------------------------------------------------------------------
// memT[b][d][m] (fp16) = mem[b][m][d] (fp32), 64x64 LDS tiles.
// Write-back is exactly 2 iterations (256 thr x 8 halfs covers 64x64).
// ---------------------------------------------------------------------------
__global__ __launch_bounds__(256) void transpose_kernel(
    const float* __restrict__ mem, _Float16* __restrict__ memT) {
  const int Lm = 2048, D = 1024;
  __shared__ _Float16 tile[64 * 68];
  int d0 = blockIdx.x * 64, m0 = blockIdx.y * 64;
  const float* src = mem + (size_t)blockIdx.z * Lm * D;
  _Float16*    dst = memT + (size_t)blockIdx.z * D * Lm;
  int tid = threadIdx.x;
  #pragma unroll
  for (int it = 0; it < 4; it++) {            // 64x64 f32, f32x4: 1024 loads
    int idx = tid + it * 256;
    int mm = idx >> 4, dc = (idx & 15) * 4;
    f32x4 v = *(const f32x4*)&src[(size_t)(m0 + mm) * D + d0 + dc];
    f16x4 h = {(_Float16)v[0], (_Float16)v[1], (_Float16)v[2], (_Float16)v[3]};
    *(f16x4*)&tile[mm * 68 + dc] = h;
  }
  __syncthreads();
  #pragma unroll
  for (int it = 0; it < 2; it++) {            // 64x64 halfs, f16x8: 512 stores
    int idx = tid + it * 256;
    int dd = idx >> 3, mc = (idx & 7) * 8;    // dd in [0,64), mc in [0,64)
    f16x8 h;
    #pragma unroll
    for (int j = 0; j < 8; j++) h[j] = tile[(mc + j) * 68 + dd];
    *(f16x8*)&dst[(size_t)(d0 + dd) * Lm + m0 + mc] = h;
  }
}

// ---------------------------------------------------------------------------
// per-row mask + softmax in place over fp16 logits; one block per (b,q) row
// ---------------------------------------------------------------------------
__global__ __launch_bounds__(256) void softmax_kernel(
    const int* __restrict__ mask, _Float16* __restrict__ wbuf) {
  const int Lm = 2048;
  size_t row = blockIdx.x;
  _Float16* wr = wbuf + row * Lm;
  const int* mr = mask + row * Lm;
  int tid = threadIdx.x;
  f16x8 lv = *(const f16x8*)&wr[tid * 8];
  const int* mp = &mr[tid * 8];
  float v[8];
  float mx = -3.0e38f;
  #pragma unroll
  for (int i = 0; i < 8; i++) {
    float l = (float)lv[i];
    if (mp[i] == 0) l += -1000000.0f;
    v[i] = l;
    mx = fmaxf(mx, l);
  }
  #pragma unroll
  for (int off = 32; off > 0; off >>= 1) mx = fmaxf(mx, __shfl_down(mx, off, 64));
  __shared__ float red[4];
  int wv = tid >> 6;
  if ((tid & 63) == 0) red[wv] = mx;
  __syncthreads();
  mx = fmaxf(fmaxf(red[0], red[1]), fmaxf(red[2], red[3]));
  __syncthreads();
  float s = 0.f;
  #pragma unroll
  for (int i = 0; i < 8; i++) { v[i] = __expf(v[i] - mx); s += v[i]; }
  #pragma unroll
  for (int off = 32; off > 0; off >>= 1) s += __shfl_down(s, off, 64);
  if ((tid & 63) == 0) red[wv] = s;
  __syncthreads();
  float inv = 1.0f / (red[0] + red[1] + red[2] + red[3]);
  f16x8 o;
  #pragma unroll
  for (int i = 0; i < 8; i++) o[i] = (_Float16)(v[i] * inv);
  *(f16x8*)&wr[tid * 8] = o;
}

// ---------------------------------------------------------------------------
// fp32 -> fp16 convert (for W), 4 elems/thread
// ---------------------------------------------------------------------------
__global__ __launch_bounds__(256) void cvt_kernel(const float* __restrict__ x,
                                                  _Float16* __restrict__ y) {
  size_t i = (size_t)(blockIdx.x * 256 + threadIdx.x) * 4;
  f32x4 v = *(const f32x4*)&x[i];
  f16x4 h = {(_Float16)v[0], (_Float16)v[1], (_Float16)v[2], (_Float16)v[3]};
  *(f16x4*)&y[i] = h;
}

// ---------------------------------------------------------------------------
// B=8, Lq=Lm=2048, Din=Dout=1024
// ws layout — exactly 96 MB total:
//   [0,32M):   qproj fp16 [B*Lq,1024] -- dead after scores; then memT fp16
//              [B,1024,2048] overwrites it (after softmax reads are done)
//   [32M,34M): Wh fp16 [1024,1024]    -- dead after proj; scores' wbuf
//              overwrites it
//   [32M,96M): wbuf fp16 [B,Lq,Lm] (logits -> softmax in place -> weights)
//
// BUGFIX (rounds 2-5 abort): pv's output batch stride was passed as
// LQM (2048*2048) but out is [B,2048,1024] -> stride LQK (2048*1024).
// Batches 4..7 wrote ~60 MB past d_out -> HSA memory fault.
// ---------------------------------------------------------------------------
extern "C" void kernel_launch(void* const* d_in, const int* in_sizes, int n_in,
                              void* d_out, int out_size, void* d_ws, size_t ws_size,
                              hipStream_t stream) {
  const float* query = (const float*)d_in[0];
  const float* mem   = (const float*)d_in[1];
  const int*   mask  = (const int*)d_in[2];
  const float* W     = (const float*)d_in[3];
  const float* bias  = (const float*)d_in[4];
  float* out = (float*)d_out;

  char* ws = (char*)d_ws;
  _Float16* qproj = (_Float16*)ws;                                // 32 MB
  _Float16* memT  = (_Float16*)ws;                                // aliases qproj
  _Float16* Wh    = (_Float16*)(ws + (size_t)32 * 1024 * 1024);   // 2 MB, transient
  _Float16* wbuf  = (_Float16*)(ws + (size_t)32 * 1024 * 1024);   // 64 MB

  const long LQK = 2048L * 1024, LQM = 2048L * 2048, LDM = 1024L * 2048;

  // W -> fp16 (into the not-yet-used wbuf region)
  cvt_kernel<<<dim3(1024), 256, 0, stream>>>(W, Wh);
  // proj: qproj[16384,1024] = query * Wh^T + b
  gemm128<_Float16, false, true, true><<<dim3(8, 128, 1), 256, 0, stream>>>(
      query, Wh, bias, qproj, 16384, 1024, 1024, 0, 0, 0);
  // scores: wbuf[b][2048,2048] = qproj * mem^T  (mem fp32, cvt in staging;
  // overwrites Wh, which is dead now)
  gemm128<_Float16, true, false, false><<<dim3(16, 16, 8), 256, 0, stream>>>(
      qproj, mem, nullptr, wbuf, 2048, 2048, 1024, LQK, LQK, LQM);
  // mask + softmax in place
  softmax_kernel<<<dim3(16384), 256, 0, stream>>>(mask, wbuf);
  // memT[b][1024,2048] = (fp16) mem^T   (qproj is dead now; reuse its space)
  transpose_kernel<<<dim3(16, 32, 8), 256, 0, stream>>>(mem, memT);
  // pv: out[b][2048,1024] = wbuf * memT^T   (sC = LQK, NOT LQM!)
  gemm128<float, true, true, false><<<dim3(8, 16, 8), 256, 0, stream>>>(
      wbuf, memT, nullptr, out, 2048, 1024, 2048, LQM, LDM, LQK);
}